// Round 9
// baseline (250.599 us; speedup 1.0000x reference)
//
#include <hip/hip_runtime.h>
#include <math.h>

// Quantum circuit simulator: BATCH=2048 states x 1024 complex amplitudes,
// QDEPTH=8 layers of StronglyEntanglingLayers (10 Rot gates + 10 CNOTs).
//
// Round-23: LAZY CNOT RELABELING — the CNOT permutations g_l are
// GF(2)-linear and compile-time known (ranges r_l=l+1, weight-indep).
// Instead of physically permuting the state through LDS every layer
// (r15-r21: 64 DS ops + an lgkmcnt join per layer = the ~39% stall that
// resisted r16-r22 scheduling attempts; r22's hand interleave regressed
// 55->92us because waiting on the newest DS read waits on ALL), keep
// storage FIXED and compose permutations into gate addressing:
//   maintain f (logical = f(phys)), f' = g^{-1} o f after each CNOT set.
//   gate on logical bit b: pair mask m = f^{-1}(e_b)  (compile-time!)
//     -> partner = register-XOR (m&7) + half-swap (m&8) + lane-XOR (m>>4)
//   hi(p) = parity(row_b(F) & p): lane part = 1 popcount/gate, t part
//     compile-time -> r21's sign-XOR coeff trick generalizes unchanged.
// All masks from a constexpr builder (m' = f^{-1}(g(e_b)) via perm_g;
// hi rows via G^{-1} row ops). One final LDS round trip (f_8^{-1})
// restores standard order before the store. DS traffic/layer: 0.
// Lane-XOR fetches: <=2 DPP (quad/mirror/ror8 compose any 4-bit mask)
// + permlane16/32_swap for bits 4/5 — all VALU pipe.
// Carried (validated r13-r21): t-packed v2f state + v_pk_fma, 4-readlane
// coeffs w/ Rot symmetry (u11r=u00r,u11i=-u00i,u10r=-u01r,u10i=u01i),
// fused single dispatch, no barriers (single wave, per-wave DS FIFO).

#define WIRES   10
#define NSTATE  1024
#define QDEPTH  8
#define NBATCH  2048
#define NGATES  (QDEPTH * WIRES)

typedef float v2f __attribute__((ext_vector_type(2)));
typedef unsigned int v2u __attribute__((ext_vector_type(2)));
static __device__ __forceinline__ v2f s2(float x) { return (v2f){x, x}; }

// ---------------- compile-time circuit structure ----------------
// index p (10 bits): bits 0-2 = k (pack), bit 3 = half (v2f lane),
// bits 4-9 = lane. Logical wire q <-> logical bit b = 9-q.
constexpr int perm_gc(int j, int r) {
    for (int q = WIRES - 1; q >= 0; --q) {
        const int cb = 9 - q;
        const int tb = 9 - ((q + r) % WIRES);
        j ^= ((j >> cb) & 1) << tb;
    }
    return j;
}

struct QTab {
    int m[QDEPTH][10];   // pair mask for gate on logical bit b, layer l
    int hi[QDEPTH][10];  // hi-parity mask (row b of F_l)
    int fin[10];         // f_8^{-1} columns (final unpermute)
};

constexpr QTab build_qtab() {
    QTab T{};
    int m[10], fr[10];
    for (int b = 0; b < 10; ++b) { m[b] = 1 << b; fr[b] = 1 << b; }
    for (int l = 0; l < QDEPTH; ++l) {
        for (int b = 0; b < 10; ++b) { T.m[l][b] = m[b]; T.hi[l][b] = fr[b]; }
        const int r = (l % (WIRES - 1)) + 1;
        int nm[10], nf[10];
        // masks: m'_b = f^{-1}(g(e_b)) = XOR_{c in g(e_b)} m_c
        for (int b = 0; b < 10; ++b) {
            const int u = perm_gc(1 << b, r);
            int acc = 0;
            for (int c = 0; c < 10; ++c) if ((u >> c) & 1) acc ^= m[c];
            nm[b] = acc;
        }
        // hi rows: F' = G^{-1} F; G^{-1} rows by reversed elementary ops
        int gi[10];
        for (int b = 0; b < 10; ++b) gi[b] = 1 << b;
        for (int q = 0; q <= 9; ++q) {
            const int cb = 9 - q;
            const int tb = 9 - ((q + r) % WIRES);
            gi[tb] ^= gi[cb];
        }
        for (int b = 0; b < 10; ++b) {
            int acc = 0;
            for (int c = 0; c < 10; ++c) if ((gi[b] >> c) & 1) acc ^= fr[c];
            nf[b] = acc;
        }
        for (int b = 0; b < 10; ++b) { m[b] = nm[b]; fr[b] = nf[b]; }
    }
    for (int b = 0; b < 10; ++b) T.fin[b] = m[b];
    return T;
}

constexpr QTab QT = build_qtab();
constexpr int word_map(int x) { return ((x & 15) << 6) | (x >> 4); }

// ---------------- cross-lane primitives ----------------
#if __has_builtin(__builtin_amdgcn_readlane)
static __device__ __forceinline__ int rli(int v, int idx) {
    return __builtin_amdgcn_readlane(v, idx);
}
#else
static __device__ __forceinline__ int rli(int v, int idx) {
    return __shfl(v, idx, 64);
}
#endif
static __device__ __forceinline__ float rlf(float v, int idx) {
    return __int_as_float(rli(__float_as_int(v), idx));
}

template<int CTRL>
__device__ __forceinline__ float dppmov(float x) {
    return __int_as_float(__builtin_amdgcn_update_dpp(
        0, __float_as_int(x), CTRL, 0xF, 0xF, true));
}

#if __has_builtin(__builtin_amdgcn_permlane16_swap)
static __device__ __forceinline__ float pl16swap(float x) {
    const v2u r = __builtin_amdgcn_permlane16_swap(
        __float_as_uint(x), __float_as_uint(x), false, false);
    return __uint_as_float((threadIdx.x & 16) ? r.x : r.y);
}
#else
static __device__ __forceinline__ float pl16swap(float x) {
    return __shfl_xor(x, 16, 64);
}
#endif

#if __has_builtin(__builtin_amdgcn_permlane32_swap)
static __device__ __forceinline__ float pl32swap(float x) {
    const v2u r = __builtin_amdgcn_permlane32_swap(
        __float_as_uint(x), __float_as_uint(x), false, false);
    return __uint_as_float((threadIdx.x & 32) ? r.x : r.y);
}
#else
static __device__ __forceinline__ float pl32swap(float x) {
    return __shfl_xor(x, 32, 64);
}
#endif

// lane-XOR by compile-time mask ML (1..63): <=2 DPP for bits 0-3
// (quad_perm xor1/2/3, half_mirror=7, ror8=8, mirror=15 compose all),
// permlane swaps for bits 4,5. Pure VALU.
template<int ML>
__device__ __forceinline__ float fxor(float x) {
    float v = x;
    constexpr int low = ML & 15;
    if constexpr (low >= 4 && low <= 7)  v = dppmov<0x141>(v);  // xor 7
    if constexpr (low >= 8 && low <= 11) v = dppmov<0x128>(v);  // xor 8
    if constexpr (low >= 12)             v = dppmov<0x140>(v);  // xor 15
    constexpr int q = (low < 4) ? low
                    : (low < 8) ? (low ^ 7)
                    : (low < 12) ? (low ^ 8) : (low ^ 15);
    if constexpr (q == 1) v = dppmov<0xB1>(v);
    if constexpr (q == 2) v = dppmov<0x4E>(v);
    if constexpr (q == 3) v = dppmov<0x1B>(v);
    if constexpr (ML & 16) v = pl16swap(v);
    if constexpr (ML & 32) v = pl32swap(v);
    return v;
}

// partner fetch: optional half-swap (MH) then lane-XOR (ML)
template<int MH, int ML>
__device__ __forceinline__ v2f fetch_pair(v2f v) {
    v2f s;
    if constexpr (MH) s = __builtin_shufflevector(v, v, 1, 0);
    else              s = v;
    if constexpr (ML != 0) { s.x = fxor<ML>(s.x); s.y = fxor<ML>(s.y); }
    return s;
}

// ---------------- gate coefficients (validated r21) ----------------
// only U00,U01 stored; u10r=-u01r, u10i=u01i, u11r=u00r, u11i=-u00i
__device__ __forceinline__ void gate_coeffs4(
    const float* __restrict__ w, int g, float (&c4)[4])
{
    const float phi   = tanhf(w[g * 3 + 0]);
    const float theta = tanhf(w[g * 3 + 1]);
    const float omega = tanhf(w[g * 3 + 2]);
    const float c  = cosf(theta * 0.5f);
    const float sn = sinf(theta * 0.5f);
    const float a  = 0.5f * (phi + omega);
    const float bb = 0.5f * (phi - omega);
    const float ca = cosf(a),  sa = sinf(a);
    const float cb = cosf(bb), sb = sinf(bb);
    c4[0] =  ca * c;   // u00r
    c4[1] = -sa * c;   // u00i
    c4[2] = -cb * sn;  // u01r
    c4[3] = -sb * sn;  // u01i
}

// ---------------- generic relabeled gate ----------------
// M = pair mask, HI = hi-parity mask. Element e: new = C0(e)*self +
// C1(e)*partner, C0=(u00r, u00i^s), C1=(u01r^s, u01i), s = hi(e)<<31.
// hi(e) = parity(HI & p) = popc(lane&hl) ^ popc(k&hk) ^ (h&hh).
template<int M, int HI>
__device__ __forceinline__ void gate_apply(
    v2f (&zr)[8], v2f (&zi)[8],
    const float u00r, const float u00i,
    const float u01r, const float u01i, const int lane)
{
    constexpr int mk = M & 7;
    constexpr int mh = (M >> 3) & 1;
    constexpr int ml = M >> 4;
    constexpr int hk = HI & 7;
    constexpr int hh = (HI >> 3) & 1;
    constexpr int hl = HI >> 4;

    unsigned sL = 0u;
    if constexpr (hl != 0)
        sL = ((unsigned)(__popc(lane & hl) & 1)) << 31;

    const float b0  = __uint_as_float(__float_as_uint(u00i) ^ sL);
    const float b0n = __uint_as_float(__float_as_uint(b0) ^ 0x80000000u);
    const float r0  = __uint_as_float(__float_as_uint(u01r) ^ sL);
    const float r0n = __uint_as_float(__float_as_uint(r0) ^ 0x80000000u);
    // per parity-class (pc = popc(k&hk)&1) coeff v2f; halves differ if hh
    const v2f C0i0 = (v2f){b0,  hh ? b0n : b0};
    const v2f C0i1 = (v2f){b0n, hh ? b0  : b0n};
    const v2f C1r0 = (v2f){r0,  hh ? r0n : r0};
    const v2f C1r1 = (v2f){r0n, hh ? r0  : r0n};
    const v2f C0r  = s2(u00r);
    const v2f C1i  = s2(u01i);

#define QG_MATH(KK, PR, PI)                                                   \
    {                                                                         \
        const bool pc1 = (__popc((KK) & hk) & 1) != 0;                        \
        const v2f C0i = pc1 ? C0i1 : C0i0;                                    \
        const v2f C1r = pc1 ? C1r1 : C1r0;                                    \
        const v2f sr = zr[(KK)], si = zi[(KK)];                               \
        zr[(KK)] = C0r*sr - C0i*si + C1r*(PR) - C1i*(PI);                     \
        zi[(KK)] = C0r*si + C0i*sr + C1r*(PI) + C1i*(PR);                     \
    }

    if constexpr (mk == 0) {
        // partner in same pack (other half and/or other lane)
#pragma unroll
        for (int k = 0; k < 8; ++k) {
            const v2f pr = fetch_pair<mh, ml>(zr[k]);
            const v2f pi = fetch_pair<mh, ml>(zi[k]);
            QG_MATH(k, pr, pi)
        }
    } else {
        // pack pairs (k0, k0^mk): fetch both partners, then write both
#pragma unroll
        for (int k0 = 0; k0 < 8; ++k0) {
            if ((k0 ^ mk) < k0) continue;     // folds after unroll
            const int k1 = k0 ^ mk;
            const v2f p0r = fetch_pair<mh, ml>(zr[k1]);
            const v2f p0i = fetch_pair<mh, ml>(zi[k1]);
            const v2f p1r = fetch_pair<mh, ml>(zr[k0]);
            const v2f p1i = fetch_pair<mh, ml>(zi[k0]);
            QG_MATH(k0, p0r, p0i)
            QG_MATH(k1, p1r, p1i)
        }
    }
#undef QG_MATH
}

// gate b of layer L with coeffs from cA/cB at readlane index G
#define GA(L, B, G) gate_apply<QT.m[L][B], QT.hi[L][B]>(zr, zi,               \
    rlf(cA[0], G), rlf(cA[1], G), rlf(cA[2], G), rlf(cA[3], G), lane);
#define GB(L, B, G) gate_apply<QT.m[L][B], QT.hi[L][B]>(zr, zi,               \
    rlf(cB[0], G), rlf(cB[1], G), rlf(cB[2], G), rlf(cB[3], G), lane);

// layer L (L<=5): gate on logical bit B = wire 9-B = coeff gate L*10+9-B
#define LAYER_A(L)                                                            \
    GA(L, 0, (L)*10 + 9) GA(L, 1, (L)*10 + 8) GA(L, 2, (L)*10 + 7)            \
    GA(L, 3, (L)*10 + 6) GA(L, 4, (L)*10 + 5) GA(L, 5, (L)*10 + 4)            \
    GA(L, 6, (L)*10 + 3) GA(L, 7, (L)*10 + 2) GA(L, 8, (L)*10 + 1)            \
    GA(L, 9, (L)*10 + 0)

__global__ __launch_bounds__(64) void qsim_lazy(
    const float* __restrict__ x,
    const float* __restrict__ weights,
    float* __restrict__ out,
    const int interleaved)
{
    __shared__ float lds[2 * NSTATE];   // final unpermute only
    const int lane = threadIdx.x;       // 0..63
    const int b    = blockIdx.x;

    // ---- prologue: 4 coeffs/gate in registers (lane g -> gate g) ----
    float cA[4], cB[4];
    gate_coeffs4(weights, lane, cA);                 // gates 0..63
    gate_coeffs4(weights, 64 + (lane & 15), cB);     // gates 64..79

    // ---- load 16 contiguous amplitudes (real input, imag = 0) ----
    v2f zr[8], zi[8];
    const float4* __restrict__ x4 =
        (const float4*)(x + ((size_t)b << 10) + (lane << 4));
    {
        const float4 v0 = x4[0], v1 = x4[1], v2 = x4[2], v3 = x4[3];
        zr[0].x=v0.x; zr[1].x=v0.y; zr[2].x=v0.z; zr[3].x=v0.w;
        zr[4].x=v1.x; zr[5].x=v1.y; zr[6].x=v1.z; zr[7].x=v1.w;
        zr[0].y=v2.x; zr[1].y=v2.y; zr[2].y=v2.z; zr[3].y=v2.w;
        zr[4].y=v3.x; zr[5].y=v3.y; zr[6].y=v3.z; zr[7].y=v3.w;
#pragma unroll
        for (int k = 0; k < 8; ++k) zi[k] = (v2f){0.f, 0.f};
    }

    // ---- 8 layers, fully unrolled, zero LDS traffic ----
    LAYER_A(0) LAYER_A(1) LAYER_A(2) LAYER_A(3) LAYER_A(4) LAYER_A(5)
    // layer 6: gates 60..63 in cA, 64..69 in cB
    GB(6, 0, 5) GB(6, 1, 4) GB(6, 2, 3) GB(6, 3, 2) GB(6, 4, 1) GB(6, 5, 0)
    GA(6, 6, 63) GA(6, 7, 62) GA(6, 8, 61) GA(6, 9, 60)
    // layer 7: gates 70..79 in cB (idx g-64 = 15-B)
    GB(7, 0, 15) GB(7, 1, 14) GB(7, 2, 13) GB(7, 3, 12) GB(7, 4, 11)
    GB(7, 5, 10) GB(7, 6,  9) GB(7, 7,  8) GB(7, 8,  7) GB(7, 9,  6)

    // ---- final unpermute: Out[i] = S[f_8^{-1}(i)], one LDS round trip ----
    // write S at word(p) = t*64 + lane (conflict-free, validated layout)
#pragma unroll
    for (int k = 0; k < 8; ++k) {
        const int w = k * 64 + lane;
        lds[w]        = zr[k].x;
        lds[w + 512]  = zr[k].y;
        lds[w + 1024] = zi[k].x;
        lds[w + 1536] = zi[k].y;
    }
    // read addr(i) = XOR of word-mapped f_8^{-1} columns over bits of i
    int base = 0;
#pragma unroll
    for (int j = 0; j < 6; ++j)
        base ^= ((lane >> j) & 1) ? word_map(QT.fin[4 + j]) : 0;
    // single wave: per-wave DS FIFO -> reads after writes, no barrier
#pragma unroll
    for (int k = 0; k < 8; ++k) {
        const int at = ((k & 1) ? word_map(QT.fin[0]) : 0)
                     ^ ((k & 2) ? word_map(QT.fin[1]) : 0)
                     ^ ((k & 4) ? word_map(QT.fin[2]) : 0);
        const int a0 = base ^ at;
        const int a1 = a0 ^ word_map(QT.fin[3]);
        zr[k].x = lds[a0]; zi[k].x = lds[a0 + 1024];
        zr[k].y = lds[a1]; zi[k].y = lds[a1 + 1024];
    }

    // ---- epilogue ----
    if (interleaved) {
        float2* __restrict__ o2 = (float2*)out;
        const size_t base2 = ((size_t)b << 10) + (lane << 4);
#pragma unroll
        for (int k = 0; k < 8; ++k) {
            o2[base2 + k]     = make_float2(zr[k].x, zi[k].x);
            o2[base2 + k + 8] = make_float2(zr[k].y, zi[k].y);
        }
    } else {
        // harness compares real part only (complex64 expected cast to f32)
        float4* __restrict__ o4 = (float4*)(out + ((size_t)b << 10) + (lane << 4));
        o4[0] = make_float4(zr[0].x, zr[1].x, zr[2].x, zr[3].x);
        o4[1] = make_float4(zr[4].x, zr[5].x, zr[6].x, zr[7].x);
        o4[2] = make_float4(zr[0].y, zr[1].y, zr[2].y, zr[3].y);
        o4[3] = make_float4(zr[4].y, zr[5].y, zr[6].y, zr[7].y);
    }
}

extern "C" void kernel_launch(void* const* d_in, const int* in_sizes, int n_in,
                              void* d_out, int out_size, void* d_ws, size_t ws_size,
                              hipStream_t stream) {
    const float* x       = (const float*)d_in[0];   // (2048,1,32,32) f32
    const float* weights = (const float*)d_in[1];   // (8,10,3) f32
    float* out = (float*)d_out;
    const int interleaved = (out_size >= 2 * NBATCH * NSTATE) ? 1 : 0;
    (void)d_ws; (void)ws_size;

    qsim_lazy<<<NBATCH, 64, 0, stream>>>(x, weights, out, interleaved);
}

// Round 10
// 106.316 us; speedup vs baseline: 2.3571x; 2.3571x over previous
//
#include <hip/hip_runtime.h>
#include <math.h>

// Quantum circuit simulator: BATCH=2048 states x 1024 complex amplitudes,
// QDEPTH=8 layers of StronglyEntanglingLayers (10 Rot gates + 10 CNOTs).
//
// Round-24: RESTORE r21 byte-identical (measured: kernel 55.0us, total
// 105.4, passed). Post-r21 experiments both catastrophically regressed:
//  - r22 (hand-interleaved CNOT reads with next wire-9): 92us. lgkmcnt
//    waits are "N oldest"; consuming the newest reads first serializes
//    4 full LDS round trips per layer. Compiler's own partial waits on
//    the straight-line form are better.
//  - r23 (lazy CNOT relabeling, zero DS per layer): 200us. 80 unrolled
//    gate bodies with dense cross-lane masks -> I-cache thrash (VALUBusy
//    27%) + dependent DPP hazard chains. The ~5.8cyc/op DS round trip
//    is far cheaper than what replaced it.
// Verdict: r21's structure is the measured optimum of 9 structural
// variants (r15-r23). Locking it in.
//
// r21 = fused single dispatch + readlane coeff distribution + Rot
// symmetry (4 readlanes/gate) + GF(2) gt-basis in one VGPR + desync
// prologue (null effect, kept for byte-identity with the 55.0us run).
// Validated core (r13-r21):
//  - state packed over t: zr[k]=(re[t=k],re[t=k+8]), zi likewise ->
//    element-wise v_pk_fma_f32 with scalar coeffs.
//  - wires 9..7: cross-pack register gates; wire 6: in-pack half-swap;
//    wires 5..2: DPP row ops; wires 1,0: permlane{16,32}_swap (VALU).
//  - CNOT: composed GF(2)-linear permutation, one LDS round trip,
//    t-major word(i)=(i&15)*64+(i>>4) (only conflict-free layout
//    measured: 1.3e5 vs 7.3e6/3.7e6 alternatives); merged re/im planes
//    -> ds_*2st64_b32 pairing; no barriers (single wave, DS FIFO).
//  - Rot symmetry: u10r=-u01r, u10i=u01i, u11r=u00r, u11i=-u00i ->
//    sign-XOR coefficient selects, signs fold into FMA neg modifiers.

#define WIRES   10
#define NSTATE  1024
#define QDEPTH  8
#define NBATCH  2048
#define NGATES  (QDEPTH * WIRES)

typedef float v2f __attribute__((ext_vector_type(2)));
typedef unsigned int v2u __attribute__((ext_vector_type(2)));
static __device__ __forceinline__ v2f s2(float x) { return (v2f){x, x}; }

__device__ __forceinline__ int perm_g(int j, int r) {
#pragma unroll
    for (int q = WIRES - 1; q >= 0; --q) {
        const int cb = 9 - q;
        const int tb = 9 - ((q + r) % WIRES);
        j ^= ((j >> cb) & 1) << tb;
    }
    return j;
}

#if __has_builtin(__builtin_amdgcn_readlane)
static __device__ __forceinline__ int rli(int v, int idx) {
    return __builtin_amdgcn_readlane(v, idx);
}
#else
static __device__ __forceinline__ int rli(int v, int idx) {
    return __shfl(v, idx, 64);
}
#endif
static __device__ __forceinline__ float rlf(float v, int idx) {
    return __int_as_float(rli(__float_as_int(v), idx));
}

// DPP cross-lane move (VALU pipe, rows of 16 lanes) — validated r9/r10/r13
template<int CTRL>
__device__ __forceinline__ float dppmov(float x) {
    return __int_as_float(__builtin_amdgcn_update_dpp(
        0, __float_as_int(x), CTRL, 0xF, 0xF, true));
}
#define FX1(v)  dppmov<0xB1>(v)
#define FX2(v)  dppmov<0x4E>(v)
#define FX4(v)  dppmov<0x1B>(dppmov<0x141>(v))
#define FX8(v)  dppmov<0x128>(v)

#if __has_builtin(__builtin_amdgcn_permlane16_swap)
static __device__ __forceinline__ float pl16swap(float x) {
    const v2u r = __builtin_amdgcn_permlane16_swap(
        __float_as_uint(x), __float_as_uint(x), false, false);
    return __uint_as_float((threadIdx.x & 16) ? r.x : r.y);
}
#define FX16(v) pl16swap(v)
#else
#define FX16(v) __shfl_xor((v), 16, 64)
#endif

#if __has_builtin(__builtin_amdgcn_permlane32_swap)
static __device__ __forceinline__ float pl32swap(float x) {
    const v2u r = __builtin_amdgcn_permlane32_swap(
        __float_as_uint(x), __float_as_uint(x), false, false);
    return __uint_as_float((threadIdx.x & 32) ? r.x : r.y);
}
#define FX32(v) pl32swap(v)
#else
#define FX32(v) __shfl_xor((v), 32, 64)
#endif

// Rot gate base coeffs: only U00,U01 stored; U10=-conj'(U01), U11=conj'(U00)
// (u10r=-u01r, u10i=u01i, u11r=u00r, u11i=-u00i).
__device__ __forceinline__ void gate_coeffs4(
    const float* __restrict__ w, int g, float (&c4)[4])
{
    const float phi   = tanhf(w[g * 3 + 0]);
    const float theta = tanhf(w[g * 3 + 1]);
    const float omega = tanhf(w[g * 3 + 2]);
    const float c  = cosf(theta * 0.5f);
    const float sn = sinf(theta * 0.5f);
    const float a  = 0.5f * (phi + omega);
    const float bb = 0.5f * (phi - omega);
    const float ca = cosf(a),  sa = sinf(a);
    const float cb = cosf(bb), sb = sinf(bb);
    c4[0] =  ca * c;   // u00r
    c4[1] = -sa * c;   // u00i
    c4[2] = -cb * sn;  // u01r
    c4[3] = -sb * sn;  // u01i
}

static __device__ __forceinline__ float sgnxor(float v, unsigned s) {
    return __uint_as_float(__float_as_uint(v) ^ s);
}

// ---- gate bodies; expect getc(q,j) (j=0..3), lane, zr, zi in scope ----
// Substituted forms (from validated originals via the symmetry):
//   zr[k1] = -u01r*a0r - u01i*a0i + u00r*a1r + u00i*a1i
//   zi[k1] = -u01r*a0i + u01i*a0r + u00r*a1i - u00i*a1r
#define LOCAL_GATE(Q, MASK)                                                   \
    {                                                                         \
        const float u00r=getc(Q,0), u00i=getc(Q,1);                           \
        const float u01r=getc(Q,2), u01i=getc(Q,3);                           \
        _Pragma("unroll")                                                     \
        for (int k0 = 0; k0 < 8; ++k0) {                                      \
            if (k0 & (MASK)) continue;                                        \
            const int k1 = k0 | (MASK);                                       \
            const v2f a0r = zr[k0], a0i = zi[k0];                             \
            const v2f a1r = zr[k1], a1i = zi[k1];                             \
            zr[k0] = s2(u00r)*a0r - s2(u00i)*a0i + s2(u01r)*a1r - s2(u01i)*a1i;\
            zi[k0] = s2(u00r)*a0i + s2(u00i)*a0r + s2(u01r)*a1i + s2(u01i)*a1r;\
            zr[k1] = s2(u00r)*a1r + s2(u00i)*a1i - s2(u01r)*a0r - s2(u01i)*a0i;\
            zi[k1] = s2(u00r)*a1i - s2(u00i)*a1r - s2(u01r)*a0i + s2(u01i)*a0r;\
        }                                                                     \
    }

// wire-6 half-swap: pAr={u00r,u11r}=s2(u00r); pAi={u00i,-u00i};
// pBr={u01r,-u01r}; pBi={u01i,u01i}=s2(u01i)
#define HSWAP_GATE(Q)                                                         \
    {                                                                         \
        const float u00r=getc(Q,0), u00i=getc(Q,1);                           \
        const float u01r=getc(Q,2), u01i=getc(Q,3);                           \
        const v2f pAr = s2(u00r);                                             \
        const v2f pAi = (v2f){u00i, -u00i};                                   \
        const v2f pBr = (v2f){u01r, -u01r};                                   \
        const v2f pBi = s2(u01i);                                             \
        _Pragma("unroll")                                                     \
        for (int k = 0; k < 8; ++k) {                                         \
            const v2f r  = zr[k], i = zi[k];                                  \
            const v2f rs = __builtin_shufflevector(r, r, 1, 0);               \
            const v2f is = __builtin_shufflevector(i, i, 1, 0);               \
            zr[k] = pAr*r - pAi*i + pBr*rs - pBi*is;                          \
            zi[k] = pAr*i + pAi*r + pBr*is + pBi*rs;                          \
        }                                                                     \
    }

// lane gate: c0r=u00r (no select), c0i=u00i^sgn, c1r=u01r^sgn, c1i=u01i
#define LANE_GATE(Q, J, FETCH)                                                \
    {                                                                         \
        const float u00r=getc(Q,0), u00i=getc(Q,1);                           \
        const float u01r=getc(Q,2), u01i=getc(Q,3);                           \
        const unsigned sgn = ((unsigned)(lane >> (J)) & 1u) << 31;            \
        const float c0r = u00r,            c0i = sgnxor(u00i, sgn);           \
        const float c1r = sgnxor(u01r, sgn), c1i = u01i;                      \
        _Pragma("unroll")                                                     \
        for (int k = 0; k < 8; ++k) {                                         \
            v2f pr, pi;                                                       \
            pr.x = FETCH(zr[k].x); pr.y = FETCH(zr[k].y);                     \
            pi.x = FETCH(zi[k].x); pi.y = FETCH(zi[k].y);                     \
            const v2f sr = zr[k], si = zi[k];                                 \
            zr[k] = s2(c0r)*sr - s2(c0i)*si + s2(c1r)*pr - s2(c1i)*pi;        \
            zi[k] = s2(c0r)*si + s2(c0i)*sr + s2(c1r)*pi + s2(c1i)*pr;        \
        }                                                                     \
    }

// one full layer: 10 rotation gates + composed-CNOT LDS round trip
template<typename GetC>
__device__ __forceinline__ void layer_body(
    v2f (&zr)[8], v2f (&zi)[8], GetC getc,
    const int G0, const int G1, const int G2, const int G3,
    const int ga, float* __restrict__ lds, const int lane)
{
    LOCAL_GATE(9, 1)
    LOCAL_GATE(8, 2)
    LOCAL_GATE(7, 4)
    HSWAP_GATE(6)
    LANE_GATE(5, 0, FX1)
    LANE_GATE(4, 1, FX2)
    LANE_GATE(3, 2, FX4)
    LANE_GATE(2, 3, FX8)
    LANE_GATE(1, 4, FX16)
    LANE_GATE(0, 5, FX32)

    // CNOT write: word(i) = t*64 + lane; 4 stores/k share base ->
    // 2x ds_write2st64_b32. Conflict-free (bank = lane mod 32).
#pragma unroll
    for (int k = 0; k < 8; ++k) {
        const int w = k * 64 + lane;
        lds[w]        = zr[k].x;
        lds[w + 512]  = zr[k].y;
        lds[w + 1024] = zi[k].x;
        lds[w + 1536] = zi[k].y;
    }
    // gt[k] = XOR of basis (SALU); single-wave DS FIFO -> no barrier.
    const int s01 = G0 ^ G1;
    const int gkt[8] = {0, G0, G1, s01, G2, G2 ^ G0, G2 ^ G1, G2 ^ s01};
#pragma unroll
    for (int k = 0; k < 8; ++k) {
        const int a0 = ga ^ gkt[k];
        const int a1 = a0 ^ G3;
        zr[k].x = lds[a0]; zi[k].x = lds[a0 + 1024];
        zr[k].y = lds[a1]; zi[k].y = lds[a1 + 1024];
    }
}

__global__ __launch_bounds__(64) void qsim_rl2(
    const float* __restrict__ x,
    const float* __restrict__ weights,
    float* __restrict__ out,
    const int interleaved)
{
    __shared__ float lds[2 * NSTATE];       // CNOT buffer: re [0,1024), im +1024
    __shared__ int   gaT[QDEPTH * 64];      // word(g_l(lane<<4)) per lane

    const int lane = threadIdx.x;           // 0..63
    const int b    = blockIdx.x;

    // ---- wave desync (kept for byte-identity with the measured 55.0us
    // run; r21 showed duty insensitive to it) ----
    for (int i = 0; i < (b & 7); ++i) __builtin_amdgcn_s_sleep(4);

    // ---- prologue: 4 coeffs/gate in registers (lane g -> gate g) ----
    float cA[4], cB[4];
    gate_coeffs4(weights, lane, cA);                 // gates 0..63
    gate_coeffs4(weights, 64 + (lane & 15), cB);     // gates 64..79

    int gv;                                 // G-basis: lane = l*4+b (l<8,b<4)
    {
        const int lg = (lane >> 2) & 7;
        const int bb = lane & 3;
        const int j  = perm_g(1 << bb, lg + 1);
        gv = ((j & 15) << 6) | (j >> 4);
    }
#pragma unroll
    for (int l = 0; l < QDEPTH; ++l) {      // ranges r_l = l+1
        const int j = perm_g(lane << 4, l + 1);
        gaT[l * 64 + lane] = ((j & 15) << 6) | (j >> 4);
    }

    // ---- load 16 contiguous amplitudes (real input, imag = 0) ----
    v2f zr[8], zi[8];
    const float4* __restrict__ x4 =
        (const float4*)(x + ((size_t)b << 10) + (lane << 4));
    {
        const float4 v0 = x4[0], v1 = x4[1], v2 = x4[2], v3 = x4[3];
        zr[0].x=v0.x; zr[1].x=v0.y; zr[2].x=v0.z; zr[3].x=v0.w;
        zr[4].x=v1.x; zr[5].x=v1.y; zr[6].x=v1.z; zr[7].x=v1.w;
        zr[0].y=v2.x; zr[1].y=v2.y; zr[2].y=v2.z; zr[3].y=v2.w;
        zr[4].y=v3.x; zr[5].y=v3.y; zr[6].y=v3.z; zr[7].y=v3.w;
#pragma unroll
        for (int k = 0; k < 8; ++k) zi[k] = (v2f){0.f, 0.f};
    }

    int ga = gaT[lane];                     // layer 0 (DS FIFO after init)

    // ---- layers 0..5: all gates in cA; runtime readlane index ----
#pragma unroll 1
    for (int l = 0; l < 6; ++l) {
        const int sb = l * 10;
        const int G0 = rli(gv, 4 * l + 0);
        const int G1 = rli(gv, 4 * l + 1);
        const int G2 = rli(gv, 4 * l + 2);
        const int G3 = rli(gv, 4 * l + 3);
        const int ga_nx = gaT[(l + 1) * 64 + lane];
        layer_body(zr, zi,
            [&](int q, int j) { return rlf(cA[j], sb + q); },
            G0, G1, G2, G3, ga, lds, lane);
        ga = ga_nx;
    }
    // ---- layer 6: gates 60..63 in cA, 64..69 in cB ----
    {
        const int G0 = rli(gv, 24), G1 = rli(gv, 25);
        const int G2 = rli(gv, 26), G3 = rli(gv, 27);
        const int ga_nx = gaT[7 * 64 + lane];
        layer_body(zr, zi,
            [&](int q, int j) {
                return (q < 4) ? rlf(cA[j], 60 + q) : rlf(cB[j], q - 4);
            },
            G0, G1, G2, G3, ga, lds, lane);
        ga = ga_nx;
    }
    // ---- layer 7: gates 70..79 in cB ----
    {
        const int G0 = rli(gv, 28), G1 = rli(gv, 29);
        const int G2 = rli(gv, 30), G3 = rli(gv, 31);
        layer_body(zr, zi,
            [&](int q, int j) { return rlf(cB[j], 6 + q); },
            G0, G1, G2, G3, ga, lds, lane);
    }

    // ---- epilogue ----
    if (interleaved) {
        float2* __restrict__ o2 = (float2*)out;
        const size_t base = ((size_t)b << 10) + (lane << 4);
#pragma unroll
        for (int k = 0; k < 8; ++k) {
            o2[base + k]     = make_float2(zr[k].x, zi[k].x);
            o2[base + k + 8] = make_float2(zr[k].y, zi[k].y);
        }
    } else {
        // harness compares real part only (complex64 expected cast to float32)
        float4* __restrict__ o4 = (float4*)(out + ((size_t)b << 10) + (lane << 4));
        o4[0] = make_float4(zr[0].x, zr[1].x, zr[2].x, zr[3].x);
        o4[1] = make_float4(zr[4].x, zr[5].x, zr[6].x, zr[7].x);
        o4[2] = make_float4(zr[0].y, zr[1].y, zr[2].y, zr[3].y);
        o4[3] = make_float4(zr[4].y, zr[5].y, zr[6].y, zr[7].y);
    }
}

extern "C" void kernel_launch(void* const* d_in, const int* in_sizes, int n_in,
                              void* d_out, int out_size, void* d_ws, size_t ws_size,
                              hipStream_t stream) {
    const float* x       = (const float*)d_in[0];   // (2048,1,32,32) f32
    const float* weights = (const float*)d_in[1];   // (8,10,3) f32
    float* out = (float*)d_out;
    const int interleaved = (out_size >= 2 * NBATCH * NSTATE) ? 1 : 0;
    (void)d_ws; (void)ws_size;

    qsim_rl2<<<NBATCH, 64, 0, stream>>>(x, weights, out, interleaved);
}